// Round 6
// baseline (198.949 us; speedup 1.0000x reference)
//
#include <hip/hip_runtime.h>
#include <stdint.h>

typedef __attribute__((ext_vector_type(4))) float f32x4;
typedef __attribute__((ext_vector_type(8))) short short8v;
typedef __attribute__((ext_vector_type(4))) unsigned short ushort4v;
typedef __attribute__((ext_vector_type(8))) unsigned short ushort8v;

__device__ __forceinline__ unsigned short f2b(float x) {
  union { float f; unsigned int u; } c; c.f = x;
  unsigned int r = (c.u + 0x7fffu + ((c.u >> 16) & 1u)) >> 16;
  return (unsigned short)r;
}

__device__ __forceinline__ float b2f(unsigned short x) {
  union { unsigned int u; float f; } c; c.u = ((unsigned int)x) << 16;
  return c.f;
}

__device__ __forceinline__ void gload_lds16(const void* g, void* l) {
  __builtin_amdgcn_global_load_lds(
      (const __attribute__((address_space(1))) void*)g,
      (__attribute__((address_space(3))) void*)l, 16, 0, 0);
}

__device__ __forceinline__ f32x4 MFMA16(short8v a, short8v b, f32x4 c) {
  return __builtin_amdgcn_mfma_f32_16x16x32_bf16(a, b, c, 0, 0, 0);
}

// fp32 -> bf16 elementwise (8 elems / thread)
__global__ __launch_bounds__(256) void cvt_bf16(const float* __restrict__ in,
                                                unsigned short* __restrict__ out,
                                                int n8) {
  for (int i = blockIdx.x * 256 + threadIdx.x; i < n8; i += gridDim.x * 256) {
    f32x4 a = *((const f32x4*)in + (size_t)i * 2);
    f32x4 b = *((const f32x4*)in + (size_t)i * 2 + 1);
    ushort8v o;
    o[0] = f2b(a[0]); o[1] = f2b(a[1]); o[2] = f2b(a[2]); o[3] = f2b(a[3]);
    o[4] = f2b(b[0]); o[5] = f2b(b[1]); o[6] = f2b(b[2]); o[7] = f2b(b[3]);
    *((ushort8v*)out + i) = o;
  }
}

// 4x 1024x1024 fp32 W[k][n] -> bf16 WT[n][k]; z selects the matrix
__global__ __launch_bounds__(256) void wt4_bf16(const float* __restrict__ w0,
                                                const float* __restrict__ w1,
                                                const float* __restrict__ w2,
                                                const float* __restrict__ w3,
                                                unsigned short* __restrict__ o0,
                                                unsigned short* __restrict__ o1,
                                                unsigned short* __restrict__ o2,
                                                unsigned short* __restrict__ o3) {
  const int z = blockIdx.z;
  const float* W = z == 0 ? w0 : z == 1 ? w1 : z == 2 ? w2 : w3;
  unsigned short* WT = z == 0 ? o0 : z == 1 ? o1 : z == 2 ? o2 : o3;
  __shared__ float t[64][65];
  const int bi = blockIdx.y * 64, bj = blockIdx.x * 64;
#pragma unroll
  for (int i = 0; i < 16; ++i) {
    int idx = i * 256 + threadIdx.x;
    int r = idx >> 6, c = idx & 63;
    t[r][c] = W[(size_t)(bi + r) * 1024 + bj + c];
  }
  __syncthreads();
#pragma unroll
  for (int i = 0; i < 16; ++i) {
    int idx = i * 256 + threadIdx.x;
    int r = idx >> 6, c = idx & 63;
    WT[(size_t)(bj + r) * 1024 + bi + c] = f2b(t[c][r]);
  }
}

// In-place row softmax over 2048 bf16 scores.
__global__ __launch_bounds__(256) void softmax_bf16(unsigned short* __restrict__ S,
                                                    long long bstride) {
  unsigned short* row = S + (long long)blockIdx.y * bstride + (size_t)blockIdx.x * 2048;
  const int t = threadIdx.x;
  ushort8v u = *((const ushort8v*)row + t);
  float v[8];
#pragma unroll
  for (int j = 0; j < 8; ++j) v[j] = b2f(u[j]);
  float m = v[0];
#pragma unroll
  for (int j = 1; j < 8; ++j) m = fmaxf(m, v[j]);
#pragma unroll
  for (int o = 32; o; o >>= 1) m = fmaxf(m, __shfl_xor(m, o));
  __shared__ float red[4];
  const int wid = t >> 6, lane = t & 63;
  if (lane == 0) red[wid] = m;
  __syncthreads();
  m = fmaxf(fmaxf(red[0], red[1]), fmaxf(red[2], red[3]));
  float s = 0.f;
#pragma unroll
  for (int j = 0; j < 8; ++j) { v[j] = __expf(v[j] - m); s += v[j]; }
#pragma unroll
  for (int o = 32; o; o >>= 1) s += __shfl_xor(s, o);
  __syncthreads();
  if (lane == 0) red[wid] = s;
  __syncthreads();
  s = red[0] + red[1] + red[2] + red[3];
  const float inv = 1.f / s;
  ushort8v o8;
#pragma unroll
  for (int j = 0; j < 8; ++j) o8[j] = f2b(v[j] * inv);
  *((ushort8v*)row + t) = o8;
}

// Row softmax over 2048 fp32; writes bf16 P in place (fallback path only).
__global__ __launch_bounds__(256) void softmax_rows(float* __restrict__ S,
                                                    long long bstride) {
  float* row = S + (long long)blockIdx.y * bstride + (size_t)blockIdx.x * 2048;
  const int t = threadIdx.x;
  f32x4 a = *(const f32x4*)(row + t * 8);
  f32x4 b = *(const f32x4*)(row + t * 8 + 4);
  float m = fmaxf(fmaxf(fmaxf(a[0], a[1]), fmaxf(a[2], a[3])),
                  fmaxf(fmaxf(b[0], b[1]), fmaxf(b[2], b[3])));
#pragma unroll
  for (int o = 32; o; o >>= 1) m = fmaxf(m, __shfl_xor(m, o));
  __shared__ float red[4];
  const int wid = t >> 6, lane = t & 63;
  if (lane == 0) red[wid] = m;
  __syncthreads();
  m = fmaxf(fmaxf(red[0], red[1]), fmaxf(red[2], red[3]));
  float e[8];
  float s = 0.f;
#pragma unroll
  for (int j = 0; j < 4; ++j) { e[j] = __expf(a[j] - m); s += e[j]; }
#pragma unroll
  for (int j = 0; j < 4; ++j) { e[4 + j] = __expf(b[j] - m); s += e[4 + j]; }
#pragma unroll
  for (int o = 32; o; o >>= 1) s += __shfl_xor(s, o);
  __syncthreads();
  if (lane == 0) red[wid] = s;
  __syncthreads();
  s = red[0] + red[1] + red[2] + red[3];
  const float inv = 1.f / s;
  ushort8v o8;
#pragma unroll
  for (int j = 0; j < 8; ++j) o8[j] = f2b(e[j] * inv);
  __syncthreads();
  *((ushort8v*)row + t) = o8;
}

// ---------------------------------------------------------------------------
// 128x256 GEMM, 3-buffer stage-2-ahead pipeline: C[M,N] = A[M,K] @ B[N,K]^T.
// 512 threads (8 waves, 2M x 4N), BK=64. LDS = 3 x (A 16KB | B 32KB) = 144KB.
// Per K-tile: stage tile t+2 (6 gload_lds) at top; 2 k-half compute phases
// (8 ds_read_b128 + 16 MFMA each, setprio-wrapped); ONE vmcnt(6) + ONE
// s_barrier at tile end. vmcnt(6) => tile t+1 fully landed (t+2's 6 loads
// stay in flight) -- the pipeline never drains mid-loop.
// Hazard proof: stage in tile t writes buf((t+2)%3); its previous readers ran
// in tile t-1 and fully drained their ds_reads (register-complete before
// MFMA) before the end-of-(t-1) barrier. The "memory" clobber on the vmcnt
// asm pins LDS reads and stage intrinsics on the correct side of barriers.
// Swizzle (both-sides involution, rule 21): 16B chunk c of row r holds
// logical k-chunk c^(r&7); applied to the GLOBAL source on staging (LDS dest
// linear) and to the ds_read column. Verified conflict-free in round 5.
// EPI: 0 = fp32 out (scale + opt bias), 1 = bf16 out (scale),
//      2 = fused QKV (col segs 0/1 -> C0/C1 bf16; seg 2 -> C2 bf16
//          transposed, ld 8192)
template <int EPI>
__global__ __launch_bounds__(512, 2) void gemm128x256(
    const unsigned short* __restrict__ A, int lda,
    const unsigned short* __restrict__ B, int ldb,
    void* __restrict__ C0, void* __restrict__ C1, void* __restrict__ C2,
    int ldc, const float* __restrict__ bias0, const float* __restrict__ bias1,
    const float* __restrict__ bias2, float scale, int K,
    long long bsA, long long bsB, long long bsC) {
  extern __shared__ __align__(16) char smem[];
  constexpr int TSZ = 49152;  // one tile: A 16384 + B 32768

  const int tid = threadIdx.x;
  const int z = blockIdx.z;
  A += (long long)z * bsA;
  B += (long long)z * bsB;
  const int blkrow = blockIdx.y * 128, blkcol = blockIdx.x * 256;
  const int lane = tid & 63, wid = tid >> 6;
  const int kblk = lane >> 4, l15 = lane & 15;
  const int wr = (wid >> 2) * 64, wc = (wid & 3) * 64;
  const int sw = l15 & 7;

  // staging map: thread -> (row = tid>>3, chunk = tid&7), pre-swizzled source
  const int srow = tid >> 3;
  const int scol = ((tid & 7) ^ (srow & 7)) << 3;  // elems
  const unsigned short* ag = A + (size_t)(blkrow + srow) * lda + scol;
  const unsigned short* bg = B + (size_t)(blkcol + srow) * ldb + scol;
  const int ldsoff = tid * 16;

  auto stage = [&](char* buf, int kt) {
    const unsigned short* a0 = ag + kt * 64;
    const unsigned short* b0 = bg + kt * 64;
    gload_lds16(a0, buf + ldsoff);                             // A rows 0-63
    gload_lds16(a0 + (size_t)64 * lda, buf + 8192 + ldsoff);   // A rows 64-127
    gload_lds16(b0, buf + 16384 + ldsoff);                     // B rows 0-63
    gload_lds16(b0 + (size_t)64 * ldb, buf + 24576 + ldsoff);
    gload_lds16(b0 + (size_t)128 * ldb, buf + 32768 + ldsoff);
    gload_lds16(b0 + (size_t)192 * ldb, buf + 40960 + ldsoff);
  };

  f32x4 acc[4][4] = {};
  const int NT = K >> 6;

  // prologue: tiles 0 and 1 in flight; wait tile 0 landed
  stage(smem, 0);
  stage(smem + TSZ, 1);
  asm volatile("s_waitcnt vmcnt(6)" ::: "memory");
  __builtin_amdgcn_s_barrier();

  char* rb = smem;            // read buffer (tile t)
  char* sb = smem + 2 * TSZ;  // stage buffer (tile t+2)
  for (int t = 0; t < NT; ++t) {
    if (t + 2 < NT) stage(sb, t + 2);
    short8v af[4], bf[4];
#pragma unroll
    for (int ks = 0; ks < 2; ++ks) {
      const int kc = ks * 4 + kblk;       // logical k-chunk 0..7
      const int sc = (kc ^ sw) << 4;      // swizzled byte col
#pragma unroll
      for (int m = 0; m < 4; ++m)
        af[m] = *(const short8v*)(rb + (wr + m * 16 + l15) * 128 + sc);
#pragma unroll
      for (int n = 0; n < 4; ++n)
        bf[n] = *(const short8v*)(rb + 16384 + (wc + n * 16 + l15) * 128 + sc);
      __builtin_amdgcn_s_setprio(1);
#pragma unroll
      for (int m = 0; m < 4; ++m)
#pragma unroll
        for (int n = 0; n < 4; ++n)
          acc[m][n] = MFMA16(af[m], bf[n], acc[m][n]);
      __builtin_amdgcn_s_setprio(0);
    }
    if (t + 1 < NT) {
      if (t + 2 < NT) asm volatile("s_waitcnt vmcnt(6)" ::: "memory");
      else            asm volatile("s_waitcnt vmcnt(0)" ::: "memory");
      __builtin_amdgcn_s_barrier();
    }
    rb += TSZ; if (rb == smem + 3 * TSZ) rb = smem;
    sb += TSZ; if (sb == smem + 3 * TSZ) sb = smem;
  }

  // epilogue: C/D mapping col = lane&15, row = (lane>>4)*4 + j (m89-verified)
  const int gr0 = blkrow + wr + kblk * 4;
  const int gc0 = blkcol + wc + l15;
  if (EPI == 0) {
    float* C = (float*)C0 + (long long)z * bsC;
#pragma unroll
    for (int m = 0; m < 4; ++m)
#pragma unroll
      for (int n = 0; n < 4; ++n) {
        const int gc = gc0 + n * 16;
        const float badd = bias0 ? bias0[gc] : 0.f;
#pragma unroll
        for (int j = 0; j < 4; ++j)
          C[(size_t)(gr0 + m * 16 + j) * ldc + gc] = acc[m][n][j] * scale + badd;
      }
  } else if (EPI == 1) {
    unsigned short* C = (unsigned short*)C0 + (long long)z * bsC;
#pragma unroll
    for (int m = 0; m < 4; ++m)
#pragma unroll
      for (int n = 0; n < 4; ++n) {
        const int gc = gc0 + n * 16;
        const float badd = bias0 ? bias0[gc] : 0.f;
#pragma unroll
        for (int j = 0; j < 4; ++j)
          C[(size_t)(gr0 + m * 16 + j) * ldc + gc] = f2b(acc[m][n][j] * scale + badd);
      }
  } else {
    const int seg = blkcol >> 10;  // 0=q, 1=k, 2=v (256-blocks never straddle)
#pragma unroll
    for (int m = 0; m < 4; ++m)
#pragma unroll
      for (int n = 0; n < 4; ++n) {
        const int gc = gc0 + n * 16;
        const int lc = gc - seg * 1024;
        if (seg < 2) {
          unsigned short* O = (unsigned short*)(seg == 0 ? C0 : C1);
          const float* bb = (seg == 0 ? bias0 : bias1);
          const float badd = bb[lc];
#pragma unroll
          for (int j = 0; j < 4; ++j)
            O[(size_t)(gr0 + m * 16 + j) * 1024 + lc] = f2b(acc[m][n][j] + badd);
        } else {
          unsigned short* O = (unsigned short*)C2;  // Vt[1024][8192]
          const float badd = bias2[lc];
          ushort4v pk;
#pragma unroll
          for (int j = 0; j < 4; ++j) pk[j] = f2b(acc[m][n][j] + badd);
          *(ushort4v*)(O + (size_t)lc * 8192 + gr0 + m * 16) = pk;
        }
      }
  }
}

// ---------------------------------------------------------------------------
// fallback m97-style 128x128 GEMM (small-ws plan only)
template <int OMODE, bool BIAS, bool SCALE>
__global__ __launch_bounds__(256, 2) void gemm_bt(
    const unsigned short* __restrict__ A, int lda,
    const unsigned short* __restrict__ B, int ldb,
    void* __restrict__ Cp, int ldc,
    const float* __restrict__ bias, float scale, int K,
    long long bsA, long long bsB, long long bsC) {
  __shared__ unsigned short As[128 * 32];
  __shared__ unsigned short Bs[128 * 32];
  const int tid = threadIdx.x;
  A += (long long)blockIdx.z * bsA;
  B += (long long)blockIdx.z * bsB;
  const int brow = blockIdx.y * 128, bcol = blockIdx.x * 128;
  const int wid = tid >> 6, lane = tid & 63;
  const int wr = (wid >> 1) * 64, wc = (wid & 1) * 64;
  const int lrow = lane & 15, kblk = lane >> 4;
  f32x4 acc[4][4] = {};
  for (int kk = 0; kk < K; kk += 32) {
#pragma unroll
    for (int r = 0; r < 2; ++r) {
      int idx = r * 256 + tid;
      int row = idx >> 2, seg = (idx & 3) * 8;
      gload_lds16(A + (size_t)(brow + row) * lda + kk + seg, (char*)As + idx * 16);
      gload_lds16(B + (size_t)(bcol + row) * ldb + kk + seg, (char*)Bs + idx * 16);
    }
    __syncthreads();
    short8v af[4], bv[4];
#pragma unroll
    for (int m = 0; m < 4; ++m)
      af[m] = *(const short8v*)(As + (wr + m * 16 + lrow) * 32 + kblk * 8);
#pragma unroll
    for (int n = 0; n < 4; ++n)
      bv[n] = *(const short8v*)(Bs + (wc + n * 16 + lrow) * 32 + kblk * 8);
#pragma unroll
    for (int m = 0; m < 4; ++m)
#pragma unroll
      for (int n = 0; n < 4; ++n)
        acc[m][n] = MFMA16(af[m], bv[n], acc[m][n]);
    __syncthreads();
  }
  const int r0 = brow + wr + kblk * 4;
  const int c0 = bcol + wc + lrow;
  if (OMODE == 0) {
    float* C = (float*)Cp + (long long)blockIdx.z * bsC;
#pragma unroll
    for (int m = 0; m < 4; ++m)
#pragma unroll
      for (int n = 0; n < 4; ++n) {
        const int cc = c0 + n * 16;
        const float badd = BIAS ? bias[cc] : 0.f;
#pragma unroll
        for (int j = 0; j < 4; ++j) {
          float v = acc[m][n][j];
          if (SCALE) v *= scale;
          C[(size_t)(r0 + m * 16 + j) * ldc + cc] = v + badd;
        }
      }
  } else if (OMODE == 1) {
    unsigned short* C = (unsigned short*)Cp + (long long)blockIdx.z * bsC;
#pragma unroll
    for (int m = 0; m < 4; ++m)
#pragma unroll
      for (int n = 0; n < 4; ++n) {
        const int cc = c0 + n * 16;
        const float badd = BIAS ? bias[cc] : 0.f;
#pragma unroll
        for (int j = 0; j < 4; ++j) {
          float v = acc[m][n][j];
          if (SCALE) v *= scale;
          C[(size_t)(r0 + m * 16 + j) * ldc + cc] = f2b(v + badd);
        }
      }
  } else {
    unsigned short* C = (unsigned short*)Cp + (long long)blockIdx.z * bsC;
#pragma unroll
    for (int m = 0; m < 4; ++m)
#pragma unroll
      for (int n = 0; n < 4; ++n) {
        const int cc = c0 + n * 16;
        const float badd = BIAS ? bias[cc] : 0.f;
        ushort4v pk;
#pragma unroll
        for (int j = 0; j < 4; ++j) {
          float v = acc[m][n][j];
          if (SCALE) v *= scale;
          pk[j] = f2b(v + badd);
        }
        *(ushort4v*)(C + (size_t)cc * ldc + (r0 + m * 16)) = pk;
      }
  }
}

extern "C" void kernel_launch(void* const* d_in, const int* in_sizes, int n_in,
                              void* d_out, int out_size, void* d_ws, size_t ws_size,
                              hipStream_t stream) {
  const float* x  = (const float*)d_in[0];
  const float* wq = (const float*)d_in[1];
  const float* bq = (const float*)d_in[2];
  const float* wk = (const float*)d_in[3];
  const float* bk = (const float*)d_in[4];
  const float* wv = (const float*)d_in[5];
  const float* bv = (const float*)d_in[6];
  const float* wo = (const float*)d_in[7];
  const float* bo = (const float*)d_in[8];
  float* out = (float*)d_out;
  char* ws = (char*)d_ws;

  const long long WELEM = 1024LL * 1024;
  const long long BATCH = 2048LL * 1024;
  const long long FULL  = 4 * BATCH;
  const long long SELEM = 2048LL * 2048;   // per-batch scores (elems)

  const size_t need_A = 8388608ull + 5ull * 16777216 + 4ull * 16777216;
  const size_t need_C = 8388608ull + 4ull * 4194304 + 16777216ull;

  if (ws_size >= need_A) {
    unsigned short* wqT = (unsigned short*)ws;
    unsigned short* wkT = wqT + WELEM;
    unsigned short* wvT = wkT + WELEM;   // wqT..wvT contiguous => [3072][1024]
    unsigned short* woT = wvT + WELEM;
    unsigned short* xb  = woT + WELEM;
    unsigned short* qb  = xb + FULL;
    unsigned short* kb  = qb + FULL;
    unsigned short* vt  = kb + FULL;     // Vt[1024][8192]
    unsigned short* ao  = vt + FULL;
    unsigned short* S   = ao + FULL;     // bf16 scores [4][2048][2048]

    hipFuncSetAttribute(reinterpret_cast<const void*>(&gemm128x256<0>),
                        hipFuncAttributeMaxDynamicSharedMemorySize, 147456);
    hipFuncSetAttribute(reinterpret_cast<const void*>(&gemm128x256<1>),
                        hipFuncAttributeMaxDynamicSharedMemorySize, 147456);
    hipFuncSetAttribute(reinterpret_cast<const void*>(&gemm128x256<2>),
                        hipFuncAttributeMaxDynamicSharedMemorySize, 147456);

    cvt_bf16<<<2048, 256, 0, stream>>>(x, xb, (int)(FULL / 8));
    wt4_bf16<<<dim3(16, 16, 4), 256, 0, stream>>>(wq, wk, wv, wo, wqT, wkT, wvT, woT);

    // fused QKV: [8192,1024] @ [3072,1024]^T, grid 12x64 = 768 blocks (3/CU rounds)
    gemm128x256<2><<<dim3(12, 64, 1), 512, 147456, stream>>>(
        xb, 1024, wqT, 1024, qb, kb, vt, 0, bq, bk, bv, 1.f, 1024, 0, 0, 0);
    // QK^T (batched): -> bf16 S, *1/32; grid 8x16x4 = 512 blocks
    gemm128x256<1><<<dim3(8, 16, 4), 512, 147456, stream>>>(
        qb, 1024, kb, 1024, S, nullptr, nullptr, 2048, nullptr, nullptr,
        nullptr, 0.03125f, 1024, BATCH, BATCH, SELEM);
    softmax_bf16<<<dim3(2048, 4), 256, 0, stream>>>(S, SELEM);
    // PV (batched): P[2048,2048]bf16 @ Vt[1024 rows, ld 8192]^T; 256 blocks
    gemm128x256<1><<<dim3(4, 16, 4), 512, 147456, stream>>>(
        S, 2048, vt, 8192, ao, nullptr, nullptr, 1024,
        nullptr, nullptr, nullptr, 1.f, 2048, SELEM, 2048, BATCH);
    // out-proj: [8192,1024] @ [1024,1024]^T + bo -> fp32; 256 blocks
    gemm128x256<0><<<dim3(4, 64, 1), 512, 147456, stream>>>(
        ao, 1024, woT, 1024, out, nullptr, nullptr, 1024, bo, nullptr, nullptr,
        1.f, 1024, 0, 0, 0);
  } else if (ws_size >= need_C) {
    unsigned short* wqT = (unsigned short*)ws;
    unsigned short* wkT = wqT + WELEM;
    unsigned short* wvT = wkT + WELEM;
    unsigned short* woT = wvT + WELEM;
    unsigned short* xb  = woT + WELEM;
    unsigned short* qb  = xb + BATCH;
    unsigned short* kb  = qb + BATCH;
    unsigned short* vtb = kb + BATCH;
    float* S = (float*)(vtb + BATCH);

    wt4_bf16<<<dim3(16, 16, 4), 256, 0, stream>>>(wq, wk, wv, wo, wqT, wkT, wvT, woT);

    for (int b = 0; b < 4; ++b) {
      cvt_bf16<<<1024, 256, 0, stream>>>(x + b * BATCH, xb, (int)(BATCH / 8));
      dim3 gqkv(8, 16);
      gemm_bt<1, true, false><<<gqkv, 256, 0, stream>>>(xb, 1024, wqT, 1024, qb, 1024, bq, 1.f, 1024, 0, 0, 0);
      gemm_bt<1, true, false><<<gqkv, 256, 0, stream>>>(xb, 1024, wkT, 1024, kb, 1024, bk, 1.f, 1024, 0, 0, 0);
      gemm_bt<2, true, false><<<gqkv, 256, 0, stream>>>(xb, 1024, wvT, 1024, vtb, 2048, bv, 1.f, 1024, 0, 0, 0);
      gemm_bt<0, false, true><<<dim3(16, 16), 256, 0, stream>>>(
          qb, 1024, kb, 1024, S, 2048, nullptr, 0.03125f, 1024, 0, 0, 0);
      softmax_rows<<<dim3(2048, 1), 256, 0, stream>>>(S, 0);
      gemm_bt<1, false, false><<<dim3(8, 16), 256, 0, stream>>>(
          (const unsigned short*)S, 4096, vtb, 2048, xb, 1024, nullptr, 1.f, 2048, 0, 0, 0);
      gemm_bt<0, true, false><<<dim3(8, 16), 256, 0, stream>>>(
          xb, 1024, woT, 1024, out + b * BATCH, 1024, bo, 1.f, 1024, 0, 0, 0);
    }
  }
}